// Round 7
// baseline (95.302 us; speedup 1.0000x reference)
//
#include <hip/hip_runtime.h>

#define W 512

__device__ __forceinline__ float fexp2(float x) {
#if __has_builtin(__builtin_amdgcn_exp2f)
    return __builtin_amdgcn_exp2f(x);
#else
    return __expf(x * 0.6931471805599453f);
#endif
}

// ---------------- tiny min/max pre-pass: 256 contention-free partials ----------------
__global__ __launch_bounds__(256) void k_minmax(const float* __restrict__ y,
                                                float2* __restrict__ partial) {
    __shared__ float smn[256], smx[256];
    int t = threadIdx.x;
    const float4* y4 = (const float4*)y;
    float4 v = y4[blockIdx.x * 256 + t];
    float mn = fminf(fminf(v.x, v.y), fminf(v.z, v.w));
    float mx = fmaxf(fmaxf(v.x, v.y), fmaxf(v.z, v.w));
    smn[t] = mn; smx[t] = mx;
    __syncthreads();
    for (int off = 128; off > 0; off >>= 1) {
        if (t < off) {
            smn[t] = fminf(smn[t], smn[t + off]);
            smx[t] = fmaxf(smx[t], smx[t + off]);
        }
        __syncthreads();
    }
    if (t == 0) partial[blockIdx.x] = make_float2(smn[0], smx[0]);
}

// ---------------- fully fused kernel: box + bilateral, all tiles LDS-resident ----
// Block: 64x8 = 512 threads, 1 px/thread -> 64x8 output tile.
// 2 blocks/CU x 8 waves = 16 waves/CU = 4 waves/SIMD (R6 was 2/SIMD, latency-bound).
__global__ __launch_bounds__(512) void k_fused(const float* __restrict__ X,
                                               const float* __restrict__ y,
                                               const float2* __restrict__ partial,
                                               const float* __restrict__ r,
                                               float* __restrict__ out) {
    __shared__ float sbx[19];   // row/col spatial weights, 19x19 filter
    __shared__ float sdy[5];    // row spatial weights, 5x9 filter
    // one LDS arena with phase-based aliasing (60256 B < 64 KB static limit)
    __shared__ __align__(16) char ldsbuf[60256];
    float*  sX  = (float*)ldsbuf;            // 34*90 staged X   (rows r0-13..r0+20, cols c0-13..c0+76)
    float*  sY  = sX + 34 * 90;              // 34*90 staged y
    float*  csX = sY + 34 * 90;              // 26*90 9-row col-sums of X
    float*  csY = csX + 26 * 90;             // 26*90
    float2* bXY = (float2*)(csY + 26 * 90);  // 26*82 (Xb,yb)    (rows r0-9..r0+16, cols c0-9..c0+72)
    float2* dXD = (float2*)csX;              // 12*72 (Xd,Dd) — aliases cs after it's dead
    float2* red = (float2*)sX;               // 256 — prologue alias, dead before staging

    int tx = threadIdx.x, ty = threadIdx.y;
    int t = ty * 64 + tx;
    int c0 = blockIdx.x * 64, r0 = blockIdx.y * 8;

    if (t < 19)      { int d = t - 9;      sbx[t]      = __expf(-(float)(d * d) / 8145.0625f); }
    else if (t < 24) { int d = t - 19 - 2; sdy[t - 19] = __expf(-(float)(d * d) / 126.5625f); }

    // ---- prologue: reduce 256 min/max partials -> k2 ----
    if (t < 256) red[t] = partial[t];
    __syncthreads();
    for (int off = 128; off > 0; off >>= 1) {
        if (t < off) {
            red[t].x = fminf(red[t].x, red[t + off].x);
            red[t].y = fmaxf(red[t].y, red[t + off].y);
        }
        __syncthreads();
    }
    float2 mm0 = red[0];
    __syncthreads();                          // red (sX alias) free for staging
    float sigma = r[0] * (mm0.y - mm0.x);
    float hh = 0.5f * sigma;
    float k2 = -1.4426950408889634f / (hh * hh);   // w_range = 2^(u^2*k2)

    // ---- stage X,y with halo (zero outside image) ----
    for (int i = t; i < 34 * 90; i += 512) {
        int rr = i / 90, cc2 = i - rr * 90;
        int gr = r0 - 13 + rr, gc = c0 - 13 + cc2;
        bool ok = ((unsigned)gr < 512u) & ((unsigned)gc < 512u);
        float xv = 0.f, yv = 0.f;
        if (ok) { xv = X[gr * W + gc]; yv = y[gr * W + gc]; }
        sX[i] = xv; sY[i] = yv;
    }
    __syncthreads();

    // ---- 9-row column sums ----
    for (int i = t; i < 26 * 90; i += 512) {
        int rr = i / 90, cc2 = i - rr * 90;
        float ax = 0.f, ay = 0.f;
#pragma unroll
        for (int k = 0; k < 9; ++k) { ax += sX[(rr + k) * 90 + cc2]; ay += sY[(rr + k) * 90 + cc2]; }
        csX[i] = ax; csY[i] = ay;
    }
    __syncthreads();

    // ---- 9-col sums -> (Xb, yb) tile ----
    const float inv81 = 1.0f / 81.0f;
    for (int i = t; i < 26 * 82; i += 512) {
        int rr = i / 82, cc2 = i - rr * 82;
        float ax = 0.f, ay = 0.f;
#pragma unroll
        for (int k = 0; k < 9; ++k) { ax += csX[rr * 90 + cc2 + k]; ay += csY[rr * 90 + cc2 + k]; }
        bXY[i] = make_float2(ax * inv81, ay * inv81);
    }
    __syncthreads();

    // ---- (Xd, Dd) detail tile (rows r0-2..r0+9, cols c0-4..c0+67); aliases cs ----
    for (int i = t; i < 12 * 72; i += 512) {
        int rr = i / 72, cc2 = i - rr * 72;
        float2 b2 = bXY[(rr + 7) * 82 + (cc2 + 5)];
        float xc = sX[(rr + 11) * 90 + (cc2 + 9)];
        float yc = sY[(rr + 11) * 90 + (cc2 + 9)];
        float xd = xc - b2.x;
        dXD[i] = make_float2(xd, (yc - b2.y) - xd);
    }
    __syncthreads();

    // ---- bilateral passes (all LDS reads), 1 px/thread ----
    int c = c0 + tx;
    int h = r0 + ty;

    // chunk mapping: output col -> owning chunk after overlap-trim
    int chunk = (c == 0) ? 0 : (c - 1) / 62;
    if (chunk > 8) chunk = 8;
    int s = 62 * chunk;
    int e = (chunk == 8) ? 512 : (s + 64);

    // column exponents (log2-domain spatial) with chunk mask folded in
    const float ksb = -1.4426950408889634f / 8145.0625f;
    const float ksd = -1.4426950408889634f / 126.5625f;
    float cc[19];
#pragma unroll
    for (int j = 0; j < 19; ++j) {
        int nc = c - 9 + j, d = j - 9;
        cc[j] = ((nc >= s) & (nc < e)) ? ksb * (float)(d * d) : -1e30f;
    }
    float ccd[9];
#pragma unroll
    for (int j = 0; j < 9; ++j) {
        int nc = c - 4 + j, d = j - 4;
        ccd[j] = ((nc >= s) & (nc < e)) ? ksd * (float)(d * d) : -1e30f;
    }

    float Xc = bXY[(ty + 9) * 82 + tx + 9].x;
    float Xd = dXD[(ty + 2) * 72 + tx + 4].x;

    // ---- base pass: 19x19 bilateral guided-filter stats ----
    float sw = 0.f, swx = 0.f, swy = 0.f, swxx = 0.f, swxy = 0.f;
#pragma unroll 1
    for (int nh = h - 9; nh <= h + 9; ++nh) {
        if ((unsigned)nh >= 512u) continue;          // wave-uniform (ty per wave)
        const float2* xr = bXY + (nh - r0 + 9) * 82 + tx;
        float ey = sbx[nh - h + 9];
        float rs = 0.f, rsx = 0.f, rsy = 0.f, rsxx = 0.f, rsxy = 0.f;
#pragma unroll
        for (int j = 0; j < 19; ++j) {
            float2 v = xr[j];
            float xv = v.x, yv = v.y;
            float u = xv - Xc;
            float a = fmaf(u * k2, u, cc[j]);
            float w = fexp2(a);
            float tt = w * xv;
            rs   += w;
            rsx  += tt;
            rsy   = fmaf(w, yv, rsy);
            rsxx  = fmaf(tt, xv, rsxx);
            rsxy  = fmaf(tt, yv, rsxy);
        }
        sw   = fmaf(ey, rs,   sw);
        swx  = fmaf(ey, rsx,  swx);
        swy  = fmaf(ey, rsy,  swy);
        swxx = fmaf(ey, rsxx, swxx);
        swxy = fmaf(ey, rsxy, swxy);
    }

    // ---- detail pass: 5(h)x9(w) bilateral on residuals ----
    float swd = 0.f, sv = 0.f;
#pragma unroll 1
    for (int nh = h - 2; nh <= h + 2; ++nh) {
        if ((unsigned)nh >= 512u) continue;
        const float2* dr2 = dXD + (nh - r0 + 2) * 72 + tx;
        float ey = sdy[nh - h + 2];
        float rs = 0.f, rv = 0.f;
#pragma unroll
        for (int j = 0; j < 9; ++j) {
            float2 v = dr2[j];
            float xd = v.x, dv = v.y;
            float u = xd - Xd;
            float a = fmaf(u * k2, u, ccd[j]);
            float w = fexp2(a);
            rs += w;
            rv  = fmaf(w, dv, rv);
        }
        swd = fmaf(ey, rs, swd);
        sv  = fmaf(ey, rv, sv);
    }

    // ---- combine & store ----
    float inv = 1.0f / sw;
    float mx = swx * inv, my = swy * inv;
    float varx = fmaf(-mx, mx, swxx * inv);
    float cov  = fmaf(-mx, my, swxy * inv);
    float A = cov / (varx + 1e-6f);
    float b = my - A * mx;
    out[h * W + c] = A * Xc + b + Xd + sv / swd;
}

extern "C" void kernel_launch(void* const* d_in, const int* in_sizes, int n_in,
                              void* d_out, int out_size, void* d_ws, size_t ws_size,
                              hipStream_t stream) {
    const float* X = (const float*)d_in[0];
    const float* y = (const float*)d_in[1];
    const float* r = (const float*)d_in[2];
    float* out = (float*)d_out;
    float2* partial = (float2*)d_ws;               // 256 float2, fully written each call

    k_minmax<<<256, 256, 0, stream>>>(y, partial);
    k_fused<<<dim3(8, 64), dim3(64, 8), 0, stream>>>(X, y, partial, r, out);
}

// Round 8
// 93.437 us; speedup vs baseline: 1.0200x; 1.0200x over previous
//
#include <hip/hip_runtime.h>

#define W 512

typedef float v2f __attribute__((ext_vector_type(2)));

__device__ __forceinline__ float fexp2(float x) {
#if __has_builtin(__builtin_amdgcn_exp2f)
    return __builtin_amdgcn_exp2f(x);
#else
    return __expf(x * 0.6931471805599453f);
#endif
}
__device__ __forceinline__ v2f vfma2(v2f a, v2f b, v2f c) {
    return __builtin_elementwise_fma(a, b, c);
}
__device__ __forceinline__ v2f bc2(float x) { v2f r; r.x = x; r.y = x; return r; }

// ---------------- tiny min/max pre-pass: 256 contention-free partials ----------------
__global__ __launch_bounds__(256) void k_minmax(const float* __restrict__ y,
                                                float2* __restrict__ partial) {
    __shared__ float smn[256], smx[256];
    int t = threadIdx.x;
    const float4* y4 = (const float4*)y;
    float4 v = y4[blockIdx.x * 256 + t];
    float mn = fminf(fminf(v.x, v.y), fminf(v.z, v.w));
    float mx = fmaxf(fmaxf(v.x, v.y), fmaxf(v.z, v.w));
    smn[t] = mn; smx[t] = mx;
    __syncthreads();
    for (int off = 128; off > 0; off >>= 1) {
        if (t < off) {
            smn[t] = fminf(smn[t], smn[t + off]);
            smx[t] = fmaxf(smx[t], smx[t + off]);
        }
        __syncthreads();
    }
    if (t == 0) partial[blockIdx.x] = make_float2(smn[0], smx[0]);
}

// ---------------- fully fused kernel: box + bilateral, all tiles LDS-resident ----
// Block: 64x8 = 512 threads, 1 px/thread -> 64x8 output tile.
// launch_bounds(512,2): VGPR cap 256 so cc[19]/ccd[9] stay register-resident
// (R7 showed VGPR_Count=52 -> compiler rematerialized masks per tap in hot loop).
__global__ __launch_bounds__(512, 2) void k_fused(const float* __restrict__ X,
                                                  const float* __restrict__ y,
                                                  const float2* __restrict__ partial,
                                                  const float* __restrict__ r,
                                                  float* __restrict__ out) {
    __shared__ float sbx[19];   // row/col spatial weights, 19x19 filter
    __shared__ float sdy[5];    // row spatial weights, 5x9 filter
    // one LDS arena with phase-based aliasing (60256 B < 64 KB static limit)
    __shared__ __align__(16) char ldsbuf[60256];
    float*  sX  = (float*)ldsbuf;            // 34*90 staged X   (rows r0-13..r0+20, cols c0-13..c0+76)
    float*  sY  = sX + 34 * 90;              // 34*90 staged y
    float*  csX = sY + 34 * 90;              // 26*90 9-row col-sums of X
    float*  csY = csX + 26 * 90;             // 26*90
    float2* bXY = (float2*)(csY + 26 * 90);  // 26*82 (Xb,yb)    (rows r0-9..r0+16, cols c0-9..c0+72)
    float2* dXD = (float2*)csX;              // 12*72 (Xd,Dd) — aliases cs after it's dead
    float2* red = (float2*)sX;               // 256 — prologue alias, dead before staging

    int tx = threadIdx.x, ty = threadIdx.y;
    int t = ty * 64 + tx;
    int c0 = blockIdx.x * 64, r0 = blockIdx.y * 8;

    if (t < 19)      { int d = t - 9;      sbx[t]      = __expf(-(float)(d * d) / 8145.0625f); }
    else if (t < 24) { int d = t - 19 - 2; sdy[t - 19] = __expf(-(float)(d * d) / 126.5625f); }

    // ---- prologue: reduce 256 min/max partials -> k2 ----
    if (t < 256) red[t] = partial[t];
    __syncthreads();
    for (int off = 128; off > 0; off >>= 1) {
        if (t < off) {
            red[t].x = fminf(red[t].x, red[t + off].x);
            red[t].y = fmaxf(red[t].y, red[t + off].y);
        }
        __syncthreads();
    }
    float2 mm0 = red[0];
    __syncthreads();                          // red (sX alias) free for staging
    float sigma = r[0] * (mm0.y - mm0.x);
    float hh = 0.5f * sigma;
    float k2 = -1.4426950408889634f / (hh * hh);   // w_range = 2^(u^2*k2)

    // ---- stage X,y with halo (zero outside image) ----
    for (int i = t; i < 34 * 90; i += 512) {
        int rr = i / 90, cc2 = i - rr * 90;
        int gr = r0 - 13 + rr, gc = c0 - 13 + cc2;
        bool ok = ((unsigned)gr < 512u) & ((unsigned)gc < 512u);
        float xv = 0.f, yv = 0.f;
        if (ok) { xv = X[gr * W + gc]; yv = y[gr * W + gc]; }
        sX[i] = xv; sY[i] = yv;
    }
    __syncthreads();

    // ---- 9-row column sums ----
    for (int i = t; i < 26 * 90; i += 512) {
        int rr = i / 90, cc2 = i - rr * 90;
        float ax = 0.f, ay = 0.f;
#pragma unroll
        for (int k = 0; k < 9; ++k) { ax += sX[(rr + k) * 90 + cc2]; ay += sY[(rr + k) * 90 + cc2]; }
        csX[i] = ax; csY[i] = ay;
    }
    __syncthreads();

    // ---- 9-col sums -> (Xb, yb) tile ----
    const float inv81 = 1.0f / 81.0f;
    for (int i = t; i < 26 * 82; i += 512) {
        int rr = i / 82, cc2 = i - rr * 82;
        float ax = 0.f, ay = 0.f;
#pragma unroll
        for (int k = 0; k < 9; ++k) { ax += csX[rr * 90 + cc2 + k]; ay += csY[rr * 90 + cc2 + k]; }
        bXY[i] = make_float2(ax * inv81, ay * inv81);
    }
    __syncthreads();

    // ---- (Xd, Dd) detail tile (rows r0-2..r0+9, cols c0-4..c0+67); aliases cs ----
    for (int i = t; i < 12 * 72; i += 512) {
        int rr = i / 72, cc2 = i - rr * 72;
        float2 b2 = bXY[(rr + 7) * 82 + (cc2 + 5)];
        float xc = sX[(rr + 11) * 90 + (cc2 + 9)];
        float yc = sY[(rr + 11) * 90 + (cc2 + 9)];
        float xd = xc - b2.x;
        dXD[i] = make_float2(xd, (yc - b2.y) - xd);
    }
    __syncthreads();

    // ---- bilateral passes (all LDS reads), 1 px/thread ----
    int c = c0 + tx;
    int h = r0 + ty;

    // chunk mapping: output col -> owning chunk after overlap-trim
    int chunk = (c == 0) ? 0 : (c - 1) / 62;
    if (chunk > 8) chunk = 8;
    int s = 62 * chunk;
    int e = (chunk == 8) ? 512 : (s + 64);

    // column exponents (log2-domain spatial) with chunk mask folded in.
    // keep register-resident (VGPR cap 256 via launch_bounds).
    const float ksb = -1.4426950408889634f / 8145.0625f;
    const float ksd = -1.4426950408889634f / 126.5625f;
    float cc[19];
#pragma unroll
    for (int j = 0; j < 19; ++j) {
        int nc = c - 9 + j, d = j - 9;
        cc[j] = ((nc >= s) & (nc < e)) ? ksb * (float)(d * d) : -1e30f;
    }
    float ccd[9];
#pragma unroll
    for (int j = 0; j < 9; ++j) {
        int nc = c - 4 + j, d = j - 4;
        ccd[j] = ((nc >= s) & (nc < e)) ? ksd * (float)(d * d) : -1e30f;
    }

    float Xc = bXY[(ty + 9) * 82 + tx + 9].x;
    float Xd = dXD[(ty + 2) * 72 + tx + 4].x;

    // ---- base pass: 19x19 bilateral guided-filter stats ----
    // accumulators: sw scalar; {swx,swy} and {swxx,swxy} as packed pairs —
    // the loaded (xn,yn) float2 is an aligned pair, so v_pk_fma applies naturally.
    float sw = 0.f;
    v2f sxy = bc2(0.f), sxxy = bc2(0.f);
#pragma unroll 1
    for (int nh = h - 9; nh <= h + 9; ++nh) {
        if ((unsigned)nh >= 512u) continue;          // wave-uniform (ty per wave)
        const float2* xr = bXY + (nh - r0 + 9) * 82 + tx;
        float ey = sbx[nh - h + 9];
        float rs = 0.f;
        v2f rxy = bc2(0.f), rxxy = bc2(0.f);
#pragma unroll
        for (int j = 0; j < 19; ++j) {
            float2 p = xr[j];
            v2f v; v.x = p.x; v.y = p.y;
            float u = p.x - Xc;
            float a = fmaf(u * k2, u, cc[j]);
            float w = fexp2(a);
            rs += w;
            float tt = w * p.x;
            rxy  = vfma2(bc2(w),  v, rxy);    // {Σw·x, Σw·y}
            rxxy = vfma2(bc2(tt), v, rxxy);   // {Σw·x², Σw·x·y}
        }
        sw   = fmaf(ey, rs, sw);
        sxy  = vfma2(bc2(ey), rxy,  sxy);
        sxxy = vfma2(bc2(ey), rxxy, sxxy);
    }

    // ---- detail pass: 5(h)x9(w) bilateral on residuals ----
    float swd = 0.f, sv = 0.f;
#pragma unroll 1
    for (int nh = h - 2; nh <= h + 2; ++nh) {
        if ((unsigned)nh >= 512u) continue;
        const float2* dr2 = dXD + (nh - r0 + 2) * 72 + tx;
        float ey = sdy[nh - h + 2];
        float rs = 0.f, rv = 0.f;
#pragma unroll
        for (int j = 0; j < 9; ++j) {
            float2 v = dr2[j];
            float u = v.x - Xd;
            float a = fmaf(u * k2, u, ccd[j]);
            float w = fexp2(a);
            rs += w;
            rv  = fmaf(w, v.y, rv);
        }
        swd = fmaf(ey, rs, swd);
        sv  = fmaf(ey, rv, sv);
    }

    // ---- combine & store ----
    float inv = 1.0f / sw;
    float mx = sxy.x * inv, my = sxy.y * inv;
    float varx = fmaf(-mx, mx, sxxy.x * inv);
    float cov  = fmaf(-mx, my, sxxy.y * inv);
    float A = cov / (varx + 1e-6f);
    float b = my - A * mx;
    out[h * W + c] = A * Xc + b + Xd + sv / swd;
}

extern "C" void kernel_launch(void* const* d_in, const int* in_sizes, int n_in,
                              void* d_out, int out_size, void* d_ws, size_t ws_size,
                              hipStream_t stream) {
    const float* X = (const float*)d_in[0];
    const float* y = (const float*)d_in[1];
    const float* r = (const float*)d_in[2];
    float* out = (float*)d_out;
    float2* partial = (float2*)d_ws;               // 256 float2, fully written each call

    k_minmax<<<256, 256, 0, stream>>>(y, partial);
    k_fused<<<dim3(8, 64), dim3(64, 8), 0, stream>>>(X, y, partial, r, out);
}